// Round 4
// baseline (28.862 us; speedup 1.0000x reference)
//
#include <hip/hip_runtime.h>

// PyQHamiltonianEvolution: N_QUBITS=20, SUPPORT=(3,8,15), BATCH=8, DIM=8
// state layout (2,)*20 + (8,) row-major, batch innermost.
// element address bit q maps: qubit q <-> bit (19-q)+3; support qubits 3/8/15
// <-> bits 19/14/7. Output = float32 REAL PART of evolved state (2^23 elems).
//
// Single fused kernel:
//   phase 1: all blocks redundantly compute U[b] = expm(-i t_b H) (8x8 complex,
//            f32 scaling-and-squaring, s=5, Taylor K=10) into LDS, planar-by-b.
//   phase 2: each thread handles 4 consecutive r (float4 I/O), 8x8 complex
//            matvec real part, scatter 8 float4 stores.

#define SUP_OFF(m) ( ((m)&4 ? 524288u : 0u) + ((m)&2 ? 16384u : 0u) + ((m)&1 ? 128u : 0u) )

__global__ __launch_bounds__(256, 4) void fused_evolve_kernel(
        const float* __restrict__ sre_g,
        const float* __restrict__ sim_g,
        const float* __restrict__ h_real,
        const float* __restrict__ h_imag,
        const float* __restrict__ t_g,
        float* __restrict__ out)
{
    __shared__ float Tre[8][64], Tim[8][64];
    __shared__ float Mre[8][64], Mim[8][64];
    __shared__ float Ere[8][64], Eim[8][64];
    __shared__ alignas(16) float Upre[512];   // [(o*8+i)*8 + b]
    __shared__ alignas(16) float Upim[512];

    const int tid = threadIdx.x;

    // ---------------- phase 1: expm, all 8 batches in parallel --------------
    // thread -> batch b = tid>>5, matrix entries e0 = tid&31 and e1 = e0+32.
    {
        const int b  = tid >> 5;
        const int e0 = tid & 31;
        const int e1 = e0 + 32;
        const int o0 = e0 >> 3, i0 = e0 & 7;
        const int o1 = e1 >> 3, i1 = e1 & 7;

        const float sc = t_g[b] * (1.0f / 32.0f);   // M = (-i t H) / 2^5
        const float m0re =  sc * h_imag[e0];
        const float m0im = -sc * h_real[e0];
        const float m1re =  sc * h_imag[e1];
        const float m1im = -sc * h_real[e1];

        Mre[b][e0] = m0re; Mim[b][e0] = m0im;
        Mre[b][e1] = m1re; Mim[b][e1] = m1im;
        Tre[b][e0] = m0re; Tim[b][e0] = m0im;
        Tre[b][e1] = m1re; Tim[b][e1] = m1im;
        float a0re = (o0 == i0 ? 1.f : 0.f) + m0re, a0im = m0im;  // E = I + M
        float a1re = (o1 == i1 ? 1.f : 0.f) + m1re, a1im = m1im;
        __syncthreads();

        // Taylor: T = T*M/k ; E += T   (k = 2..10)
        for (int k = 2; k <= 10; ++k) {
            float s0re = 0.f, s0im = 0.f, s1re = 0.f, s1im = 0.f;
            #pragma unroll
            for (int j = 0; j < 8; ++j) {
                float tre = Tre[b][o0 * 8 + j], tim = Tim[b][o0 * 8 + j];
                float mre = Mre[b][j * 8 + i0], mim = Mim[b][j * 8 + i0];
                s0re += tre * mre - tim * mim;
                s0im += tre * mim + tim * mre;
                tre = Tre[b][o1 * 8 + j]; tim = Tim[b][o1 * 8 + j];
                mre = Mre[b][j * 8 + i1]; mim = Mim[b][j * 8 + i1];
                s1re += tre * mre - tim * mim;
                s1im += tre * mim + tim * mre;
            }
            const float inv = 1.0f / (float)k;
            s0re *= inv; s0im *= inv; s1re *= inv; s1im *= inv;
            __syncthreads();
            Tre[b][e0] = s0re; Tim[b][e0] = s0im;
            Tre[b][e1] = s1re; Tim[b][e1] = s1im;
            a0re += s0re; a0im += s0im;
            a1re += s1re; a1im += s1im;
            __syncthreads();
        }

        Ere[b][e0] = a0re; Eim[b][e0] = a0im;
        Ere[b][e1] = a1re; Eim[b][e1] = a1im;
        __syncthreads();

        // Square 5 times: E = E*E (last one writes planar U)
        for (int sq = 0; sq < 5; ++sq) {
            float s0re = 0.f, s0im = 0.f, s1re = 0.f, s1im = 0.f;
            #pragma unroll
            for (int j = 0; j < 8; ++j) {
                float xre = Ere[b][o0 * 8 + j], xim = Eim[b][o0 * 8 + j];
                float yre = Ere[b][j * 8 + i0], yim = Eim[b][j * 8 + i0];
                s0re += xre * yre - xim * yim;
                s0im += xre * yim + xim * yre;
                xre = Ere[b][o1 * 8 + j]; xim = Eim[b][o1 * 8 + j];
                yre = Ere[b][j * 8 + i1]; yim = Eim[b][j * 8 + i1];
                s1re += xre * yre - xim * yim;
                s1im += xre * yim + xim * yre;
            }
            __syncthreads();
            if (sq < 4) {
                Ere[b][e0] = s0re; Eim[b][e0] = s0im;
                Ere[b][e1] = s1re; Eim[b][e1] = s1im;
            } else {
                Upre[e0 * 8 + b] = s0re; Upim[e0 * 8 + b] = s0im;
                Upre[e1 * 8 + b] = s1re; Upim[e1 * 8 + b] = s1im;
            }
            __syncthreads();
        }
    }

    // ---------------- phase 2: apply, 4 consecutive r per thread ------------
    const int r0 = (blockIdx.x * 256 + tid) << 2;     // r0..r0+3, r0 in [0,2^20)
    unsigned addr = (r0 & 0x7Fu)
                  | ((r0 & 0x1F80u)  << 1)
                  | ((r0 & 0x1E000u) << 2)
                  | ((r0 & 0xE0000u) << 3);
    const int b0 = r0 & 7;                            // 0 or 4 (batches b0..b0+3)

    float4 xre[8], xim[8];
    #pragma unroll
    for (int i = 0; i < 8; ++i) {
        const unsigned off = addr + SUP_OFF(i);
        xre[i] = *(const float4*)(sre_g + off);
        xim[i] = *(const float4*)(sim_g + off);
    }

    #pragma unroll
    for (int o = 0; o < 8; ++o) {
        float4 a = make_float4(0.f, 0.f, 0.f, 0.f);
        #pragma unroll
        for (int i = 0; i < 8; ++i) {
            const float4 ur = *(const float4*)&Upre[(o * 8 + i) * 8 + b0];
            const float4 ui = *(const float4*)&Upim[(o * 8 + i) * 8 + b0];
            a.x += ur.x * xre[i].x - ui.x * xim[i].x;
            a.y += ur.y * xre[i].y - ui.y * xim[i].y;
            a.z += ur.z * xre[i].z - ui.z * xim[i].z;
            a.w += ur.w * xre[i].w - ui.w * xim[i].w;
        }
        *(float4*)(out + addr + SUP_OFF(o)) = a;
    }
}

extern "C" void kernel_launch(void* const* d_in, const int* in_sizes, int n_in,
                              void* d_out, int out_size, void* d_ws, size_t ws_size,
                              hipStream_t stream) {
    const float* state_real = (const float*)d_in[0];
    const float* state_imag = (const float*)d_in[1];
    const float* h_real     = (const float*)d_in[2];
    const float* h_imag     = (const float*)d_in[3];
    const float* t          = (const float*)d_in[4];

    // 2^20 r-combos / 4 per thread / 256 per block = 1024 blocks
    fused_evolve_kernel<<<1024, 256, 0, stream>>>(state_real, state_imag,
                                                  h_real, h_imag, t,
                                                  (float*)d_out);
}